// Round 6
// baseline (2029.745 us; speedup 1.0000x reference)
//
#include <hip/hip_runtime.h>
#include <math.h>
#include <stdint.h>

#define NTAGS 512
#define SEQL  512
#define BATCH 64
#define START_TAG 510
#define STOP_TAG  511
#define NEG_INF  -10000.0f

#define NB    16                // blocks; block b owns rows [32b, 32b+32) and batches [4b, 4b+4)
#define BT    1024              // 16 waves; wave w owns rows 32*bid + 2w, +1
#define WAVES 16
#define ROWS  32
#define BPB   4

// ws layout (bytes)
#define WS_NUM_OFF  0                     // float numerator accumulator
#define WS_SLOT_OFF 256                   // uint64 slots [2][NTAGS]: (tag<<32)|f32bits
#define WS_BYTES    (WS_SLOT_OFF + 2 * NTAGS * 8)

#define AGLD(p) __hip_atomic_load((p), __ATOMIC_RELAXED, __HIP_MEMORY_SCOPE_AGENT)

__global__ __launch_bounds__(BT) void crf_fused(
    const float* __restrict__ inputs, const int* __restrict__ tags,
    const float* __restrict__ trans, void* __restrict__ ws,
    float* __restrict__ out)
{
    __shared__ float t_lds[ROWS * NTAGS];   // 64 KB: my 32 transition rows
    __shared__ float fv_lds[2][NTAGS];      // 4 KB ping-pong forward variable
    __shared__ float nred[WAVES];

    const int tid  = threadIdx.x;
    const int bid  = blockIdx.x;
    const int lane = tid & 63;
    const int wave = tid >> 6;
    const int r0   = bid * ROWS + wave * 2;   // my rows: r0, r0+1

    float*    numacc = (float*)((char*)ws + WS_NUM_OFF);
    uint64_t* slots  = (uint64_t*)((char*)ws + WS_SLOT_OFF);

    // ---- stage my 32 transition rows into LDS (coalesced float4) ----
    {
        const float4* src = (const float4*)(trans + (size_t)bid * ROWS * NTAGS);
        float4*       dst = (float4*)t_lds;
        #pragma unroll
        for (int k = 0; k < ROWS * NTAGS / 4 / BT; ++k)   // 4 iters
            dst[tid + k * BT] = src[tid + k * BT];
    }

    // ---- numerator: 4 batches/block; 1024 threads = 2 batch-lanes x 512 pos ----
    float ns = 0.0f;
    {
        const int sub = tid >> 9;       // 0/1
        const int pos = tid & 511;
        #pragma unroll
        for (int bb = 0; bb < 2; ++bb) {
            const int b = bid * BPB + bb * 2 + sub;
            const int*   tg  = tags + b * SEQL;
            const float* inb = inputs + (size_t)b * SEQL * NTAGS;
            if (pos > 0) {
                const int cur = tg[pos], prev = tg[pos - 1];
                ns += trans[cur * NTAGS + prev] + inb[(size_t)(pos - 1) * NTAGS + cur];
            } else {
                ns += trans[tg[0] * NTAGS + START_TAG] + trans[STOP_TAG * NTAGS + tg[SEQL - 1]];
            }
        }
    }
    #pragma unroll
    for (int off = 32; off; off >>= 1) ns += __shfl_xor(ns, off);
    if (lane == 0) nred[wave] = ns;

    // init fv0 in LDS ping buffer 0
    if (tid < NTAGS) fv_lds[0][tid] = (tid == START_TAG) ? 0.0f : NEG_INF;
    __syncthreads();
    if (tid == 0) {                     // one atomic per block
        float t = 0.0f;
        #pragma unroll
        for (int i = 0; i < WAVES; ++i) t += nred[i];
        atomicAdd(numacc, t);
    }

    const float* trA = t_lds + (size_t)(wave * 2 + 0) * NTAGS;
    const float* trB = trA + NTAGS;

    // sum-shift = previous step's row max (step-0 values known analytically)
    float mprevA = (r0     == START_TAG) ? NEG_INF : 0.0f;
    float mprevB = (r0 + 1 == START_TAG) ? NEG_INF : 0.0f;

    for (int s = 0; s < SEQL; ++s) {
        const int pp = (s + 1) & 1;
        uint64_t* buf = slots + (unsigned)pp * NTAGS;
        const unsigned want = (unsigned)(s + 1);
        const float* fvc = fv_lds[s & 1];

        // early probe (waves 0-7 only poll): overlaps compute + publish
        uint64_t p = 0;
        if (tid < NTAGS) p = AGLD(&buf[tid]);

        // ---- both rows share the fv loads; per-row T adds ----
        float f[8], vA[8], vB[8];
        #pragma unroll
        for (int q = 0; q < 8; ++q) {                // 2-way LDS alias only (free)
            f[q]  = fvc[lane + 64 * q];
            vA[q] = f[q] + trA[lane + 64 * q];
            vB[q] = f[q] + trB[lane + 64 * q];
        }
        float mA = fmaxf(fmaxf(fmaxf(vA[0], vA[1]), fmaxf(vA[2], vA[3])),
                         fmaxf(fmaxf(vA[4], vA[5]), fmaxf(vA[6], vA[7])));
        float mB = fmaxf(fmaxf(fmaxf(vB[0], vB[1]), fmaxf(vB[2], vB[3])),
                         fmaxf(fmaxf(vB[4], vB[5]), fmaxf(vB[6], vB[7])));
        float ssA = ((__expf(vA[0] - mprevA) + __expf(vA[1] - mprevA))
                   + (__expf(vA[2] - mprevA) + __expf(vA[3] - mprevA)))
                  + ((__expf(vA[4] - mprevA) + __expf(vA[5] - mprevA))
                   + (__expf(vA[6] - mprevA) + __expf(vA[7] - mprevA)));
        float ssB = ((__expf(vB[0] - mprevB) + __expf(vB[1] - mprevB))
                   + (__expf(vB[2] - mprevB) + __expf(vB[3] - mprevB)))
                  + ((__expf(vB[4] - mprevB) + __expf(vB[5] - mprevB))
                   + (__expf(vB[6] - mprevB) + __expf(vB[7] - mprevB)));

        // four INDEPENDENT butterfly streams -> single 6-stage latency
        #pragma unroll
        for (int off = 32; off; off >>= 1) {
            const float a1 = __shfl_xor(mA, off);
            const float a2 = __shfl_xor(ssA, off);
            const float b1 = __shfl_xor(mB, off);
            const float b2 = __shfl_xor(ssB, off);
            mA = fmaxf(mA, a1); ssA += a2;
            mB = fmaxf(mB, b1); ssB += b2;
        }

        // fv'[r] = log(ss) + mprev - m ; publish lanes 0-1 -> consecutive slots
        {
            const float nvA = __logf(ssA) + mprevA - mA;
            const float nvB = __logf(ssB) + mprevB - mB;
            if (lane < 2) {
                const float nv = lane ? nvB : nvA;
                const uint64_t pk = ((uint64_t)want << 32) | (uint64_t)__float_as_uint(nv);
                __hip_atomic_store(&buf[r0 + lane], pk, __ATOMIC_RELAXED, __HIP_MEMORY_SCOPE_AGENT);
            }
        }
        mprevA = mA; mprevB = mB;   // wave-uniform after butterfly

        // ---- pipelined poll (waves 0-7), 4 independent loads in flight ----
        if (tid < NTAGS) {
            uint64_t* myslot = &buf[tid];
            if ((unsigned)(p >> 32) != want) {
                uint64_t q0 = AGLD(myslot), q1 = AGLD(myslot),
                         q2 = AGLD(myslot), q3 = AGLD(myslot);
                for (;;) {
                    if ((unsigned)(q0 >> 32) == want) { p = q0; break; }
                    q0 = AGLD(myslot);
                    if ((unsigned)(q1 >> 32) == want) { p = q1; break; }
                    q1 = AGLD(myslot);
                    if ((unsigned)(q2 >> 32) == want) { p = q2; break; }
                    q2 = AGLD(myslot);
                    if ((unsigned)(q3 >> 32) == want) { p = q3; break; }
                    q3 = AGLD(myslot);
                }
            }
            fv_lds[pp][tid] = __uint_as_float((unsigned)(p & 0xFFFFFFFFu));
        }
        __syncthreads();   // depth-2 ping-pong: one sync per step suffices
    }

    // ---- terminal by the wave that owns row STOP (block 15, wave 15, row B) ----
    if (bid == NB - 1 && wave == WAVES - 1) {
        const float* fvf = fv_lds[0];               // tag 512 lives in buffer 0
        float v[8];
        #pragma unroll
        for (int q = 0; q < 8; ++q)
            v[q] = fvf[lane + 64 * q] + trB[lane + 64 * q];
        float m = fmaxf(fmaxf(fmaxf(v[0], v[1]), fmaxf(v[2], v[3])),
                        fmaxf(fmaxf(v[4], v[5]), fmaxf(v[6], v[7])));
        // safe unshifted sum: real terms bounded by e^~11
        float ss = ((__expf(v[0]) + __expf(v[1])) + (__expf(v[2]) + __expf(v[3])))
                 + ((__expf(v[4]) + __expf(v[5])) + (__expf(v[6]) + __expf(v[7])));
        #pragma unroll
        for (int off = 32; off; off >>= 1) {
            const float ms  = __shfl_xor(m, off);
            const float sss = __shfl_xor(ss, off);
            m  = fmaxf(m, ms);
            ss += sss;
        }
        if (lane == 0) {
            const float ld  = __logf(ss) - m;       // log_denominator
            const float num = AGLD(numacc);
            out[0] = num - (float)BATCH * ld;
        }
    }
}

extern "C" void kernel_launch(void* const* d_in, const int* in_sizes, int n_in,
                              void* d_out, int out_size, void* d_ws, size_t ws_size,
                              hipStream_t stream)
{
    const float* inputs = (const float*)d_in[0];   // (64, 512, 512) fp32
    const int*   tags   = (const int*)  d_in[1];   // (64, 512) int32
    const float* trans  = (const float*)d_in[2];   // (512, 512) fp32
    float* out = (float*)d_out;

    // zero numerator accumulator + tag slots (valid tags are 1..512)
    hipMemsetAsync(d_ws, 0, WS_BYTES, stream);

    crf_fused<<<NB, BT, 0, stream>>>(inputs, tags, trans, d_ws, out);
}